// Round 2
// baseline (2681.048 us; speedup 1.0000x reference)
//
#include <hip/hip_runtime.h>
#include <hip/hip_bf16.h>
#include <cstdint>

// Problem dims
#define B_   8
#define S_   2048
#define D_   1024
#define P_   1365
#define M_   (B_*S_)      // 16384 rows
#define NGC  5460         // 4*P (i,f,o gates + cell)
#define NGCP 5504         // padded to 43*128
#define KP   1408         // P padded to 22*64

typedef __attribute__((ext_vector_type(8))) short bf16x8;
typedef __attribute__((ext_vector_type(4))) float f32x4;

__device__ __forceinline__ float fast_tanh(float x) {
  float e = __expf(2.0f * x);
  return 1.0f - 2.0f / (e + 1.0f);
}
__device__ __forceinline__ float softcap_sig(float x) {
  float t = fast_tanh(x * (1.0f / 15.0f));
  return 1.0f / (1.0f + __expf(-15.0f * t));
}
__device__ __forceinline__ void gload_lds16(const void* g, void* l) {
  __builtin_amdgcn_global_load_lds(
      (const __attribute__((address_space(1))) uint32_t*)g,
      (__attribute__((address_space(3))) uint32_t*)l,
      16, 0, 0);
}

// ---- prep: weights f32 -> bf16, padded ----
__global__ void k_prep_wgc(const float* __restrict__ gate_w,
                           const float* __restrict__ cell_w,
                           __hip_bfloat16* __restrict__ wgc) {
  int gid = blockIdx.x * blockDim.x + threadIdx.x;
  int idx = gid * 4;                       // 5504*1024 total elems
  int r = idx >> 10, c = idx & 1023;
  float4 v;
  if (r < 3 * P_) v = *(const float4*)(gate_w + (size_t)r * D_ + c);
  else if (r < NGC) v = *(const float4*)(cell_w + (size_t)(r - 3 * P_) * D_ + c);
  else v = make_float4(0.f, 0.f, 0.f, 0.f);
  __hip_bfloat16* dst = wgc + idx;
  dst[0] = __float2bfloat16(v.x); dst[1] = __float2bfloat16(v.y);
  dst[2] = __float2bfloat16(v.z); dst[3] = __float2bfloat16(v.w);
}

__global__ void k_prep_wout(const float* __restrict__ out_w,
                            __hip_bfloat16* __restrict__ wout) {
  int gid = blockIdx.x * blockDim.x + threadIdx.x;
  int idx = gid * 4;                       // 1024*1408 total elems
  int d = idx / KP, p = idx - d * KP;
  __hip_bfloat16* dst = wout + idx;
  #pragma unroll
  for (int j = 0; j < 4; ++j) {
    int pp = p + j;
    float v = (pp < P_) ? out_w[(size_t)d * P_ + pp] : 0.f;
    dst[j] = __float2bfloat16(v);
  }
}

// ---- RMSNorm: per row of D=1024, write bf16 ----
__global__ __launch_bounds__(256) void k_rmsnorm(const float* __restrict__ x,
                                                 const float* __restrict__ w,
                                                 __hip_bfloat16* __restrict__ xn) {
  __shared__ float red[4];
  int m = blockIdx.x;
  int tid = threadIdx.x;
  float4 v = ((const float4*)(x + (size_t)m * D_))[tid];
  float ss = v.x * v.x + v.y * v.y + v.z * v.z + v.w * v.w;
  #pragma unroll
  for (int off = 32; off > 0; off >>= 1) ss += __shfl_down(ss, off);
  if ((tid & 63) == 0) red[tid >> 6] = ss;
  __syncthreads();
  float tot = red[0] + red[1] + red[2] + red[3];
  float scale = rsqrtf(tot * (1.0f / (float)D_) + 1e-6f);
  float4 wv = ((const float4*)w)[tid];
  __hip_bfloat16* o = xn + (size_t)m * D_ + tid * 4;
  o[0] = __float2bfloat16(v.x * scale * wv.x);
  o[1] = __float2bfloat16(v.y * scale * wv.y);
  o[2] = __float2bfloat16(v.z * scale * wv.z);
  o[3] = __float2bfloat16(v.w * scale * wv.w);
}

// ---- fused gates+cell GEMM over one S-chunk, activation epilogue ----
#define BM 128
#define BN 128
#define BK 64
__global__ __launch_bounds__(256) void k_gemm_gates(
    const __hip_bfloat16* __restrict__ A,   // M x 1024 (xn, full)
    const __hip_bfloat16* __restrict__ Bw,  // NGCP x 1024
    __hip_bfloat16* __restrict__ pi, __hip_bfloat16* __restrict__ pf,
    __hip_bfloat16* __restrict__ po, __hip_bfloat16* __restrict__ ptc,
    int s0, int Sc) {
  __shared__ __align__(16) __hip_bfloat16 lA[BM * BK];
  __shared__ __align__(16) __hip_bfloat16 lB[BN * BK];
  const int tid = threadIdx.x;
  const int lane = tid & 63;
  const int wid = tid >> 6;
  const int wm = wid >> 1, wn = wid & 1;
  const int lr = lane & 15, lg = lane >> 4;
  const int rl0 = blockIdx.y * BM;          // chunk-local row (b*Sc + sl)
  const int bb = rl0 / Sc;
  const int arow0 = bb * S_ + s0 + (rl0 - bb * Sc);  // global row in xn
  const int col0 = blockIdx.x * BN;
  const int K = D_;

  const f32x4 zero = {0.f, 0.f, 0.f, 0.f};
  f32x4 acc[4][4];
  #pragma unroll
  for (int i = 0; i < 4; ++i)
    #pragma unroll
    for (int j = 0; j < 4; ++j) acc[i][j] = zero;

  for (int kt = 0; kt < K / BK; ++kt) {
    __syncthreads();
    #pragma unroll
    for (int it = 0; it < 4; ++it) {
      int off = (it * 256 + tid) * 8;
      int r = off >> 6, c = off & 63;
      gload_lds16(A + (size_t)(arow0 + r) * K + kt * BK + c, &lA[off]);
      gload_lds16(Bw + (size_t)(col0 + r) * K + kt * BK + c, &lB[off]);
    }
    __syncthreads();
    #pragma unroll
    for (int ks = 0; ks < 2; ++ks) {
      bf16x8 af[4], bfr[4];
      #pragma unroll
      for (int mi = 0; mi < 4; ++mi)
        af[mi] = *(const bf16x8*)&lA[(wm * 64 + mi * 16 + lr) * BK + ks * 32 + lg * 8];
      #pragma unroll
      for (int ni = 0; ni < 4; ++ni)
        bfr[ni] = *(const bf16x8*)&lB[(wn * 64 + ni * 16 + lr) * BK + ks * 32 + lg * 8];
      #pragma unroll
      for (int mi = 0; mi < 4; ++mi)
        #pragma unroll
        for (int ni = 0; ni < 4; ++ni)
          acc[mi][ni] = __builtin_amdgcn_mfma_f32_16x16x32_bf16(af[mi], bfr[ni], acc[mi][ni], 0, 0, 0);
    }
  }

  #pragma unroll
  for (int ni = 0; ni < 4; ++ni) {
    int gn = col0 + wn * 64 + ni * 16 + lr;
    if (gn >= NGC) continue;
    int g, p;
    if (gn < P_)            { g = 0; p = gn; }
    else if (gn < 2 * P_)   { g = 1; p = gn - P_; }
    else if (gn < 3 * P_)   { g = 2; p = gn - 2 * P_; }
    else                    { g = 3; p = gn - 3 * P_; }
    __hip_bfloat16* plane = (g == 0) ? pi : (g == 1) ? pf : (g == 2) ? po : ptc;
    #pragma unroll
    for (int mi = 0; mi < 4; ++mi) {
      #pragma unroll
      for (int j = 0; j < 4; ++j) {
        int rl = rl0 + wm * 64 + mi * 16 + lg * 4 + j;   // chunk-local row
        float v = acc[mi][ni][j];
        float r = (g == 3) ? fast_tanh(v) : softcap_sig(v);
        plane[(size_t)rl * KP + p] = __float2bfloat16(r);
      }
    }
  }
}

// ---- sequential scan over one S-chunk; writes y in-place into ptc ----
__global__ __launch_bounds__(256) void k_scan(
    const __hip_bfloat16* __restrict__ pi, const __hip_bfloat16* __restrict__ pf,
    const __hip_bfloat16* __restrict__ po, __hip_bfloat16* __restrict__ ptc,
    const float* __restrict__ h_in, float* __restrict__ h_out, int Sc) {
  int t = blockIdx.x * blockDim.x + threadIdx.x;  // 0..B_*KP-1
  int b = t / KP;
  int p = t - b * KP;
  size_t base = (size_t)b * Sc * KP + p;
  if (p >= P_) {  // zero-fill K-padding of y plane
    for (int sl = 0; sl < Sc; ++sl)
      ptc[base + (size_t)sl * KP] = __float2bfloat16(0.f);
    return;
  }
  float h = h_in[(size_t)b * P_ + p];
  #pragma unroll 8
  for (int sl = 0; sl < Sc; ++sl) {
    size_t idx = base + (size_t)sl * KP;
    float fi = __bfloat162float(pi[idx]);
    float ff = __bfloat162float(pf[idx]);
    float fo = __bfloat162float(po[idx]);
    float tc = __bfloat162float(ptc[idx]);
    h = ff * h + fi * tc;
    ptc[idx] = __float2bfloat16(fo * fast_tanh(h));
  }
  h_out[(size_t)b * P_ + p] = h;
}

// ---- out GEMM over one S-chunk: out = x + y(chunk,KP) @ Wout(1024,KP)^T ----
__global__ __launch_bounds__(256) void k_gemm_out(
    const __hip_bfloat16* __restrict__ A,   // (B_*Sc) x KP (y plane)
    const __hip_bfloat16* __restrict__ Bw,  // 1024 x KP
    const float* __restrict__ xres,
    float* __restrict__ out, int s0, int Sc) {
  __shared__ __align__(16) __hip_bfloat16 lA[BM * BK];
  __shared__ __align__(16) __hip_bfloat16 lB[BN * BK];
  const int tid = threadIdx.x;
  const int lane = tid & 63;
  const int wid = tid >> 6;
  const int wm = wid >> 1, wn = wid & 1;
  const int lr = lane & 15, lg = lane >> 4;
  const int rl0 = blockIdx.y * BM;
  const int bb = rl0 / Sc;
  const int grow0 = bb * S_ + s0 + (rl0 - bb * Sc);  // global output row
  const int col0 = blockIdx.x * BN;
  const int K = KP;

  const f32x4 zero = {0.f, 0.f, 0.f, 0.f};
  f32x4 acc[4][4];
  #pragma unroll
  for (int i = 0; i < 4; ++i)
    #pragma unroll
    for (int j = 0; j < 4; ++j) acc[i][j] = zero;

  for (int kt = 0; kt < K / BK; ++kt) {
    __syncthreads();
    #pragma unroll
    for (int it = 0; it < 4; ++it) {
      int off = (it * 256 + tid) * 8;
      int r = off >> 6, c = off & 63;
      gload_lds16(A + (size_t)(rl0 + r) * K + kt * BK + c, &lA[off]);
      gload_lds16(Bw + (size_t)(col0 + r) * K + kt * BK + c, &lB[off]);
    }
    __syncthreads();
    #pragma unroll
    for (int ks = 0; ks < 2; ++ks) {
      bf16x8 af[4], bfr[4];
      #pragma unroll
      for (int mi = 0; mi < 4; ++mi)
        af[mi] = *(const bf16x8*)&lA[(wm * 64 + mi * 16 + lr) * BK + ks * 32 + lg * 8];
      #pragma unroll
      for (int ni = 0; ni < 4; ++ni)
        bfr[ni] = *(const bf16x8*)&lB[(wn * 64 + ni * 16 + lr) * BK + ks * 32 + lg * 8];
      #pragma unroll
      for (int mi = 0; mi < 4; ++mi)
        #pragma unroll
        for (int ni = 0; ni < 4; ++ni)
          acc[mi][ni] = __builtin_amdgcn_mfma_f32_16x16x32_bf16(af[mi], bfr[ni], acc[mi][ni], 0, 0, 0);
    }
  }

  #pragma unroll
  for (int ni = 0; ni < 4; ++ni) {
    int gn = col0 + wn * 64 + ni * 16 + lr;
    #pragma unroll
    for (int mi = 0; mi < 4; ++mi) {
      #pragma unroll
      for (int j = 0; j < 4; ++j) {
        int grow = grow0 + wm * 64 + mi * 16 + lg * 4 + j;
        size_t o = (size_t)grow * D_ + gn;
        out[o] = xres[o] + acc[mi][ni][j];
      }
    }
  }
}

extern "C" void kernel_launch(void* const* d_in, const int* in_sizes, int n_in,
                              void* d_out, int out_size, void* d_ws, size_t ws_size,
                              hipStream_t stream) {
  const float* x      = (const float*)d_in[0];
  const float* h0     = (const float*)d_in[1];
  const float* lnw    = (const float*)d_in[2];
  const float* gate_w = (const float*)d_in[3];
  const float* cell_w = (const float*)d_in[4];
  const float* out_w  = (const float*)d_in[5];
  float* out  = (float*)d_out;
  float* hfin = out + (size_t)M_ * D_;

  // fixed workspace
  size_t off = 0;
  char* ws = (char*)d_ws;
  __hip_bfloat16* xn   = (__hip_bfloat16*)(ws + off); off += (size_t)M_ * D_ * 2;
  __hip_bfloat16* wgc  = (__hip_bfloat16*)(ws + off); off += (size_t)NGCP * D_ * 2;
  __hip_bfloat16* wout = (__hip_bfloat16*)(ws + off); off += (size_t)D_ * KP * 2;
  float* hbuf          = (float*)(ws + off);          off += (size_t)B_ * P_ * 4;
  off = (off + 255) & ~(size_t)255;

  // pick nchunks so 4 gate planes fit in remaining ws (deterministic: ws_size const)
  int nchunks = 1;
  while (nchunks < 16) {
    size_t planes = 4ull * B_ * (S_ / nchunks) * KP * 2;
    if (off + planes <= ws_size) break;
    nchunks <<= 1;
  }
  const int Sc = S_ / nchunks;
  __hip_bfloat16* pi  = (__hip_bfloat16*)(ws + off); off += (size_t)B_ * Sc * KP * 2;
  __hip_bfloat16* pf  = (__hip_bfloat16*)(ws + off); off += (size_t)B_ * Sc * KP * 2;
  __hip_bfloat16* po  = (__hip_bfloat16*)(ws + off); off += (size_t)B_ * Sc * KP * 2;
  __hip_bfloat16* ptc = (__hip_bfloat16*)(ws + off); off += (size_t)B_ * Sc * KP * 2;

  k_prep_wgc<<<dim3(NGCP * D_ / 1024), dim3(256), 0, stream>>>(gate_w, cell_w, wgc);
  k_prep_wout<<<dim3(D_ * KP / 1024), dim3(256), 0, stream>>>(out_w, wout);
  k_rmsnorm<<<dim3(M_), dim3(256), 0, stream>>>(x, lnw, xn);

  for (int c = 0; c < nchunks; ++c) {
    int s0 = c * Sc;
    k_gemm_gates<<<dim3(NGCP / BN, B_ * Sc / BM), dim3(256), 0, stream>>>(
        xn, wgc, pi, pf, po, ptc, s0, Sc);
    k_scan<<<dim3(B_ * KP / 256), dim3(256), 0, stream>>>(
        pi, pf, po, ptc, (c == 0) ? h0 : hbuf,
        (c == nchunks - 1) ? hfin : hbuf, Sc);
    k_gemm_out<<<dim3(D_ / BN, B_ * Sc / BM), dim3(256), 0, stream>>>(
        ptc, wout, x, out, s0, Sc);
  }
}

// Round 3
// 558.920 us; speedup vs baseline: 4.7968x; 4.7968x over previous
//
#include <hip/hip_runtime.h>
#include <hip/hip_bf16.h>
#include <cstdint>

// Problem dims
#define B_   8
#define S_   2048
#define D_   1024
#define P_   1365
#define M_   (B_*S_)      // 16384 rows
#define NGC  5460         // 4*P (i,f,o gates + cell)
#define NGCP 5504         // padded to 43*128
#define KP   1408         // P padded to 22*64
#define CHUNK 32          // scan chunk length
#define CMAX (S_/CHUNK)   // 64

typedef __attribute__((ext_vector_type(8))) short bf16x8;
typedef __attribute__((ext_vector_type(4))) float f32x4;

__device__ __forceinline__ float fast_tanh(float x) {
  float e = __expf(2.0f * x);
  return 1.0f - 2.0f / (e + 1.0f);
}
__device__ __forceinline__ float softcap_sig(float x) {
  float t = fast_tanh(x * (1.0f / 15.0f));
  return 1.0f / (1.0f + __expf(-15.0f * t));
}
__device__ __forceinline__ float bf2f(unsigned short u) {
  union { float f; unsigned int i; } x; x.i = ((unsigned)u) << 16; return x.f;
}
__device__ __forceinline__ unsigned short f2bf(float f) {
  __hip_bfloat16 h = __float2bfloat16(f);
  return *reinterpret_cast<unsigned short*>(&h);
}
__device__ __forceinline__ void gload_lds16(const void* g, void* l) {
  __builtin_amdgcn_global_load_lds(
      (const __attribute__((address_space(1))) uint32_t*)g,
      (__attribute__((address_space(3))) uint32_t*)l,
      16, 0, 0);
}

// ---- prep: weights f32 -> bf16, padded ----
__global__ void k_prep_wgc(const float* __restrict__ gate_w,
                           const float* __restrict__ cell_w,
                           __hip_bfloat16* __restrict__ wgc) {
  int gid = blockIdx.x * blockDim.x + threadIdx.x;
  int idx = gid * 4;                       // 5504*1024 total elems
  int r = idx >> 10, c = idx & 1023;
  float4 v;
  if (r < 3 * P_) v = *(const float4*)(gate_w + (size_t)r * D_ + c);
  else if (r < NGC) v = *(const float4*)(cell_w + (size_t)(r - 3 * P_) * D_ + c);
  else v = make_float4(0.f, 0.f, 0.f, 0.f);
  __hip_bfloat16* dst = wgc + idx;
  dst[0] = __float2bfloat16(v.x); dst[1] = __float2bfloat16(v.y);
  dst[2] = __float2bfloat16(v.z); dst[3] = __float2bfloat16(v.w);
}

__global__ void k_prep_wout(const float* __restrict__ out_w,
                            __hip_bfloat16* __restrict__ wout) {
  int gid = blockIdx.x * blockDim.x + threadIdx.x;
  int idx = gid * 4;                       // 1024*1408 total elems
  int d = idx / KP, p = idx - d * KP;
  __hip_bfloat16* dst = wout + idx;
  #pragma unroll
  for (int j = 0; j < 4; ++j) {
    int pp = p + j;
    float v = (pp < P_) ? out_w[(size_t)d * P_ + pp] : 0.f;
    dst[j] = __float2bfloat16(v);
  }
}

// ---- RMSNorm: per row of D=1024, write bf16 ----
__global__ __launch_bounds__(256) void k_rmsnorm(const float* __restrict__ x,
                                                 const float* __restrict__ w,
                                                 __hip_bfloat16* __restrict__ xn) {
  __shared__ float red[4];
  int m = blockIdx.x;
  int tid = threadIdx.x;
  float4 v = ((const float4*)(x + (size_t)m * D_))[tid];
  float ss = v.x * v.x + v.y * v.y + v.z * v.z + v.w * v.w;
  #pragma unroll
  for (int off = 32; off > 0; off >>= 1) ss += __shfl_down(ss, off);
  if ((tid & 63) == 0) red[tid >> 6] = ss;
  __syncthreads();
  float tot = red[0] + red[1] + red[2] + red[3];
  float scale = rsqrtf(tot * (1.0f / (float)D_) + 1e-6f);
  float4 wv = ((const float4*)w)[tid];
  __hip_bfloat16* o = xn + (size_t)m * D_ + tid * 4;
  o[0] = __float2bfloat16(v.x * scale * wv.x);
  o[1] = __float2bfloat16(v.y * scale * wv.y);
  o[2] = __float2bfloat16(v.z * scale * wv.z);
  o[3] = __float2bfloat16(v.w * scale * wv.w);
}

// ---- fused gates+cell GEMM over one S-chunk, activation epilogue ----
#define BM 128
#define BN 128
#define BK 64
__global__ __launch_bounds__(256) void k_gemm_gates(
    const __hip_bfloat16* __restrict__ A,   // M x 1024 (xn, full)
    const __hip_bfloat16* __restrict__ Bw,  // NGCP x 1024
    __hip_bfloat16* __restrict__ pi, __hip_bfloat16* __restrict__ pf,
    __hip_bfloat16* __restrict__ po, __hip_bfloat16* __restrict__ ptc,
    int s0, int Sc) {
  __shared__ __align__(16) __hip_bfloat16 lA[BM * BK];
  __shared__ __align__(16) __hip_bfloat16 lB[BN * BK];
  const int tid = threadIdx.x;
  const int lane = tid & 63;
  const int wid = tid >> 6;
  const int wm = wid >> 1, wn = wid & 1;
  const int lr = lane & 15, lg = lane >> 4;
  const int rl0 = blockIdx.y * BM;          // chunk-local row (b*Sc + sl)
  const int bb = rl0 / Sc;
  const int arow0 = bb * S_ + s0 + (rl0 - bb * Sc);  // global row in xn
  const int col0 = blockIdx.x * BN;
  const int K = D_;

  const f32x4 zero = {0.f, 0.f, 0.f, 0.f};
  f32x4 acc[4][4];
  #pragma unroll
  for (int i = 0; i < 4; ++i)
    #pragma unroll
    for (int j = 0; j < 4; ++j) acc[i][j] = zero;

  for (int kt = 0; kt < K / BK; ++kt) {
    __syncthreads();
    #pragma unroll
    for (int it = 0; it < 4; ++it) {
      int off = (it * 256 + tid) * 8;
      int r = off >> 6, c = off & 63;
      gload_lds16(A + (size_t)(arow0 + r) * K + kt * BK + c, &lA[off]);
      gload_lds16(Bw + (size_t)(col0 + r) * K + kt * BK + c, &lB[off]);
    }
    __syncthreads();
    #pragma unroll
    for (int ks = 0; ks < 2; ++ks) {
      bf16x8 af[4], bfr[4];
      #pragma unroll
      for (int mi = 0; mi < 4; ++mi)
        af[mi] = *(const bf16x8*)&lA[(wm * 64 + mi * 16 + lr) * BK + ks * 32 + lg * 8];
      #pragma unroll
      for (int ni = 0; ni < 4; ++ni)
        bfr[ni] = *(const bf16x8*)&lB[(wn * 64 + ni * 16 + lr) * BK + ks * 32 + lg * 8];
      #pragma unroll
      for (int mi = 0; mi < 4; ++mi)
        #pragma unroll
        for (int ni = 0; ni < 4; ++ni)
          acc[mi][ni] = __builtin_amdgcn_mfma_f32_16x16x32_bf16(af[mi], bfr[ni], acc[mi][ni], 0, 0, 0);
    }
  }

  #pragma unroll
  for (int ni = 0; ni < 4; ++ni) {
    int gn = col0 + wn * 64 + ni * 16 + lr;
    if (gn >= NGC) continue;
    int g, p;
    if (gn < P_)            { g = 0; p = gn; }
    else if (gn < 2 * P_)   { g = 1; p = gn - P_; }
    else if (gn < 3 * P_)   { g = 2; p = gn - 2 * P_; }
    else                    { g = 3; p = gn - 3 * P_; }
    __hip_bfloat16* plane = (g == 0) ? pi : (g == 1) ? pf : (g == 2) ? po : ptc;
    #pragma unroll
    for (int mi = 0; mi < 4; ++mi) {
      #pragma unroll
      for (int j = 0; j < 4; ++j) {
        int rl = rl0 + wm * 64 + mi * 16 + lg * 4 + j;   // chunk-local row
        float v = acc[mi][ni][j];
        float r = (g == 3) ? fast_tanh(v) : softcap_sig(v);
        plane[(size_t)rl * KP + p] = __float2bfloat16(r);
      }
    }
  }
}

// ---- scan pass 1: per-chunk affine map (A = prod f, B = chunk output with h_in=0) ----
__global__ __launch_bounds__(256) void k_scan_p1(
    const __hip_bfloat16* __restrict__ pi, const __hip_bfloat16* __restrict__ pf,
    const __hip_bfloat16* __restrict__ ptc,
    float* __restrict__ Abuf, float* __restrict__ Bbuf, int C) {
  int t = blockIdx.x * blockDim.x + threadIdx.x;   // B_*C*(KP/4) threads
  int p4 = t % (KP / 4);
  int rest = t / (KP / 4);
  int b = rest & 7;
  int c = rest >> 3;
  int p = p4 * 4;
  size_t base = ((size_t)b * C * CHUNK + (size_t)c * CHUNK) * KP + p;
  float4 A = make_float4(1.f, 1.f, 1.f, 1.f);
  float4 Bc = make_float4(0.f, 0.f, 0.f, 0.f);
  #pragma unroll 8
  for (int sl = 0; sl < CHUNK; ++sl) {
    size_t idx = base + (size_t)sl * KP;
    ushort4 vf = *reinterpret_cast<const ushort4*>(pf + idx);
    ushort4 vi = *reinterpret_cast<const ushort4*>(pi + idx);
    ushort4 vt = *reinterpret_cast<const ushort4*>(ptc + idx);
    float f0 = bf2f(vf.x), f1 = bf2f(vf.y), f2 = bf2f(vf.z), f3 = bf2f(vf.w);
    A.x *= f0; A.y *= f1; A.z *= f2; A.w *= f3;
    Bc.x = f0 * Bc.x + bf2f(vi.x) * bf2f(vt.x);
    Bc.y = f1 * Bc.y + bf2f(vi.y) * bf2f(vt.y);
    Bc.z = f2 * Bc.z + bf2f(vi.z) * bf2f(vt.z);
    Bc.w = f3 * Bc.w + bf2f(vi.w) * bf2f(vt.w);
  }
  size_t o = ((size_t)c * B_ + b) * KP + p;
  *reinterpret_cast<float4*>(Abuf + o) = A;
  *reinterpret_cast<float4*>(Bbuf + o) = Bc;
}

// ---- scan pass 2: compose chunk maps sequentially; emit per-chunk carry-in + h_final ----
__global__ __launch_bounds__(256) void k_scan_p2(
    const float* __restrict__ Abuf, const float* __restrict__ Bbuf,
    const float* __restrict__ h_in, float* __restrict__ carry,
    float* __restrict__ h_out, int C) {
  int t = blockIdx.x * blockDim.x + threadIdx.x;   // B_*KP threads
  int b = t / KP;
  int p = t - b * KP;
  float h = (p < P_) ? h_in[(size_t)b * P_ + p] : 0.f;
  #pragma unroll 8
  for (int c = 0; c < C; ++c) {
    size_t o = ((size_t)c * B_ + b) * KP + p;
    carry[o] = h;
    h = Abuf[o] * h + Bbuf[o];
  }
  if (p < P_) h_out[(size_t)b * P_ + p] = h;
}

// ---- scan pass 3: replay recurrence from correct carry-in; y = o*tanh(h) in-place into ptc ----
__global__ __launch_bounds__(256) void k_scan_p3(
    const __hip_bfloat16* __restrict__ pi, const __hip_bfloat16* __restrict__ pf,
    const __hip_bfloat16* __restrict__ po, __hip_bfloat16* __restrict__ ptc,
    const float* __restrict__ carry, int C) {
  int t = blockIdx.x * blockDim.x + threadIdx.x;
  int p4 = t % (KP / 4);
  int rest = t / (KP / 4);
  int b = rest & 7;
  int c = rest >> 3;
  int p = p4 * 4;
  float4 h4 = *reinterpret_cast<const float4*>(carry + ((size_t)c * B_ + b) * KP + p);
  size_t base = ((size_t)b * C * CHUNK + (size_t)c * CHUNK) * KP + p;
  #pragma unroll 4
  for (int sl = 0; sl < CHUNK; ++sl) {
    size_t idx = base + (size_t)sl * KP;
    ushort4 vf = *reinterpret_cast<const ushort4*>(pf + idx);
    ushort4 vi = *reinterpret_cast<const ushort4*>(pi + idx);
    ushort4 vo = *reinterpret_cast<const ushort4*>(po + idx);
    ushort4 vt = *reinterpret_cast<const ushort4*>(ptc + idx);
    h4.x = bf2f(vf.x) * h4.x + bf2f(vi.x) * bf2f(vt.x);
    h4.y = bf2f(vf.y) * h4.y + bf2f(vi.y) * bf2f(vt.y);
    h4.z = bf2f(vf.z) * h4.z + bf2f(vi.z) * bf2f(vt.z);
    h4.w = bf2f(vf.w) * h4.w + bf2f(vi.w) * bf2f(vt.w);
    ushort4 y;
    y.x = f2bf(bf2f(vo.x) * fast_tanh(h4.x));
    y.y = f2bf(bf2f(vo.y) * fast_tanh(h4.y));
    y.z = f2bf(bf2f(vo.z) * fast_tanh(h4.z));
    y.w = f2bf(bf2f(vo.w) * fast_tanh(h4.w));
    *reinterpret_cast<ushort4*>(ptc + idx) = y;
  }
}

// ---- out GEMM over one S-chunk: out = x + y(chunk,KP) @ Wout(1024,KP)^T ----
__global__ __launch_bounds__(256) void k_gemm_out(
    const __hip_bfloat16* __restrict__ A,   // (B_*Sc) x KP (y plane)
    const __hip_bfloat16* __restrict__ Bw,  // 1024 x KP
    const float* __restrict__ xres,
    float* __restrict__ out, int s0, int Sc) {
  __shared__ __align__(16) __hip_bfloat16 lA[BM * BK];
  __shared__ __align__(16) __hip_bfloat16 lB[BN * BK];
  const int tid = threadIdx.x;
  const int lane = tid & 63;
  const int wid = tid >> 6;
  const int wm = wid >> 1, wn = wid & 1;
  const int lr = lane & 15, lg = lane >> 4;
  const int rl0 = blockIdx.y * BM;
  const int bb = rl0 / Sc;
  const int grow0 = bb * S_ + s0 + (rl0 - bb * Sc);  // global output row
  const int col0 = blockIdx.x * BN;
  const int K = KP;

  const f32x4 zero = {0.f, 0.f, 0.f, 0.f};
  f32x4 acc[4][4];
  #pragma unroll
  for (int i = 0; i < 4; ++i)
    #pragma unroll
    for (int j = 0; j < 4; ++j) acc[i][j] = zero;

  for (int kt = 0; kt < K / BK; ++kt) {
    __syncthreads();
    #pragma unroll
    for (int it = 0; it < 4; ++it) {
      int off = (it * 256 + tid) * 8;
      int r = off >> 6, c = off & 63;
      gload_lds16(A + (size_t)(rl0 + r) * K + kt * BK + c, &lA[off]);
      gload_lds16(Bw + (size_t)(col0 + r) * K + kt * BK + c, &lB[off]);
    }
    __syncthreads();
    #pragma unroll
    for (int ks = 0; ks < 2; ++ks) {
      bf16x8 af[4], bfr[4];
      #pragma unroll
      for (int mi = 0; mi < 4; ++mi)
        af[mi] = *(const bf16x8*)&lA[(wm * 64 + mi * 16 + lr) * BK + ks * 32 + lg * 8];
      #pragma unroll
      for (int ni = 0; ni < 4; ++ni)
        bfr[ni] = *(const bf16x8*)&lB[(wn * 64 + ni * 16 + lr) * BK + ks * 32 + lg * 8];
      #pragma unroll
      for (int mi = 0; mi < 4; ++mi)
        #pragma unroll
        for (int ni = 0; ni < 4; ++ni)
          acc[mi][ni] = __builtin_amdgcn_mfma_f32_16x16x32_bf16(af[mi], bfr[ni], acc[mi][ni], 0, 0, 0);
    }
  }

  #pragma unroll
  for (int ni = 0; ni < 4; ++ni) {
    int gn = col0 + wn * 64 + ni * 16 + lr;
    #pragma unroll
    for (int mi = 0; mi < 4; ++mi) {
      #pragma unroll
      for (int j = 0; j < 4; ++j) {
        int grow = grow0 + wm * 64 + mi * 16 + lg * 4 + j;
        size_t o = (size_t)grow * D_ + gn;
        out[o] = xres[o] + acc[mi][ni][j];
      }
    }
  }
}

extern "C" void kernel_launch(void* const* d_in, const int* in_sizes, int n_in,
                              void* d_out, int out_size, void* d_ws, size_t ws_size,
                              hipStream_t stream) {
  const float* x      = (const float*)d_in[0];
  const float* h0     = (const float*)d_in[1];
  const float* lnw    = (const float*)d_in[2];
  const float* gate_w = (const float*)d_in[3];
  const float* cell_w = (const float*)d_in[4];
  const float* out_w  = (const float*)d_in[5];
  float* out  = (float*)d_out;
  float* hfin = out + (size_t)M_ * D_;

  // fixed workspace
  size_t off = 0;
  char* ws = (char*)d_ws;
  __hip_bfloat16* xn   = (__hip_bfloat16*)(ws + off); off += (size_t)M_ * D_ * 2;
  __hip_bfloat16* wgc  = (__hip_bfloat16*)(ws + off); off += (size_t)NGCP * D_ * 2;
  __hip_bfloat16* wout = (__hip_bfloat16*)(ws + off); off += (size_t)D_ * KP * 2;
  float* hbuf          = (float*)(ws + off);          off += (size_t)B_ * P_ * 4;
  float* Abuf          = (float*)(ws + off);          off += (size_t)CMAX * B_ * KP * 4;
  float* Bbuf          = (float*)(ws + off);          off += (size_t)CMAX * B_ * KP * 4;
  float* carry         = (float*)(ws + off);          off += (size_t)CMAX * B_ * KP * 4;
  off = (off + 255) & ~(size_t)255;

  // pick nchunks so 4 gate planes fit in remaining ws (deterministic: ws_size const)
  int nchunks = 1;
  while (nchunks < 16) {
    size_t planes = 4ull * B_ * (S_ / nchunks) * KP * 2;
    if (off + planes <= ws_size) break;
    nchunks <<= 1;
  }
  const int Sc = S_ / nchunks;
  const int C = Sc / CHUNK;
  __hip_bfloat16* pi  = (__hip_bfloat16*)(ws + off); off += (size_t)B_ * Sc * KP * 2;
  __hip_bfloat16* pf  = (__hip_bfloat16*)(ws + off); off += (size_t)B_ * Sc * KP * 2;
  __hip_bfloat16* po  = (__hip_bfloat16*)(ws + off); off += (size_t)B_ * Sc * KP * 2;
  __hip_bfloat16* ptc = (__hip_bfloat16*)(ws + off); off += (size_t)B_ * Sc * KP * 2;

  k_prep_wgc<<<dim3(NGCP * D_ / 1024), dim3(256), 0, stream>>>(gate_w, cell_w, wgc);
  k_prep_wout<<<dim3(D_ * KP / 1024), dim3(256), 0, stream>>>(out_w, wout);
  k_rmsnorm<<<dim3(M_), dim3(256), 0, stream>>>(x, lnw, xn);

  for (int c = 0; c < nchunks; ++c) {
    int s0 = c * Sc;
    k_gemm_gates<<<dim3(NGCP / BN, B_ * Sc / BM), dim3(256), 0, stream>>>(
        xn, wgc, pi, pf, po, ptc, s0, Sc);
    int np1 = B_ * C * (KP / 4);   // divisible by 256 (KP/4*8 = 2816 = 11*256)
    k_scan_p1<<<dim3(np1 / 256), dim3(256), 0, stream>>>(pi, pf, ptc, Abuf, Bbuf, C);
    k_scan_p2<<<dim3(B_ * KP / 256), dim3(256), 0, stream>>>(
        Abuf, Bbuf, (c == 0) ? h0 : hbuf, carry,
        (c == nchunks - 1) ? hfin : hbuf, C);
    k_scan_p3<<<dim3(np1 / 256), dim3(256), 0, stream>>>(pi, pf, po, ptc, carry, C);
    k_gemm_out<<<dim3(D_ / BN, B_ * Sc / BM), dim3(256), 0, stream>>>(
        ptc, wout, x, out, s0, Sc);
  }
}